// Round 3
// baseline (4098.312 us; speedup 1.0000x reference)
//
#include <hip/hip_runtime.h>
#include <math.h>

// ---------------------------------------------------------------------------
// BiLSTM(2 layers) + CRF NER.  T=256 B=512 V=50000 E=300 H=100 K=8
// All fp32 (no fp32 MFMA; bf16 would risk Viterbi argmax flips).
// ws budget measured R2: exactly 256 MiB (268,435,456 B).
// Layout (float offsets), total 66,616,000 fl = 266.46 MB:
//   [0, 40,000,000)          P0[50000][800] vocab proj (live: gemm->lstm0)
//       after lstm0 (P0 dead), region recycled:
//         h2  @ 0            [26,214,400]
//         XPF @ 26,214,400   [ 6,553,600]  (TC=32 x 512 x 400)
//         XPB @ 32,768,000   [ 6,553,600]
//         em  @ 26,214,400   [ 1,048,576]  (after layer1; XP dead)
//   [40,000,000, 66,214,400) h1[131072][200]
//   [66,214,400, 66,455,200) W0[240,000]+B0[800]  (dead after vocab gemm)
//         aliased later:     stH[102,400] @66,214,400, stC @66,316,800
//   [66,455,200, 66,616,000) W1[160,000]+B1[800]
// ---------------------------------------------------------------------------

#define T_LEN 256
#define B_SZ  512
#define TCH   32
#define NB    4

__device__ __forceinline__ float sigm(float x) { return 1.f / (1.f + __expf(-x)); }
__device__ __forceinline__ float tanh_f(float x) {
  float e = __expf(-2.f * fabsf(x));
  float r = (1.f - e) / (1.f + e);
  return copysignf(r, x);
}

// --------------------------- pack kernel -----------------------------------
__global__ __launch_bounds__(256) void pack_kernel(
    const float* __restrict__ wih0f, const float* __restrict__ bih0f, const float* __restrict__ bhh0f,
    const float* __restrict__ wih0b, const float* __restrict__ bih0b, const float* __restrict__ bhh0b,
    const float* __restrict__ wih1f, const float* __restrict__ bih1f, const float* __restrict__ bhh1f,
    const float* __restrict__ wih1b, const float* __restrict__ bih1b, const float* __restrict__ bhh1b,
    float* __restrict__ W0, float* __restrict__ B0,
    float* __restrict__ W1, float* __restrict__ B1,
    float* __restrict__ out0) {
  int idx = blockIdx.x * blockDim.x + threadIdx.x;
  int stride = gridDim.x * blockDim.x;
  if (idx == 0) out0[0] = 0.f;
  for (int i = idx; i < 800 * 300; i += stride) {
    int g = i / 300, d = i - g * 300;
    W0[i] = (g < 400) ? wih0f[g * 300 + d] : wih0b[(g - 400) * 300 + d];
  }
  for (int i = idx; i < 800 * 200; i += stride) {
    int g = i / 200, d = i - g * 200;
    W1[i] = (g < 400) ? wih1f[g * 200 + d] : wih1b[(g - 400) * 200 + d];
  }
  for (int i = idx; i < 800; i += stride) {
    B0[i] = (i < 400) ? (bih0f[i] + bhh0f[i]) : (bih0b[i - 400] + bhh0b[i - 400]);
    B1[i] = (i < 400) ? (bih1f[i] + bhh1f[i]) : (bih1b[i - 400] + bhh1b[i - 400]);
  }
}

// --------------------------- generic fp32 GEMM -----------------------------
// C[M][N] = A[M][Kd] . W[N][Kd]^T + bias[N].  128x128 tile, 8x8 micro, BK=8.
#define BM 128
#define BN 128
#define BK 8
__global__ __launch_bounds__(256, 2) void gemm_tn(
    const float* __restrict__ A, const float* __restrict__ W,
    const float* __restrict__ bias, float* __restrict__ C,
    int M, int N, int Kd) {
  __shared__ float As[BK][BM];
  __shared__ float Ws[BK][BN];
  const int tid = threadIdx.x;
  const int m0 = blockIdx.x * BM;
  const int n0 = blockIdx.y * BN;
  const int tx = tid & 15, ty = tid >> 4;
  const int lm = tid >> 1;
  const int lk = (tid & 1) * 4;

  float acc[8][8];
  float bj[8];
#pragma unroll
  for (int j = 0; j < 8; ++j) {
    int n = n0 + tx * 8 + j;
    bj[j] = (n < N) ? bias[n] : 0.f;
  }
#pragma unroll
  for (int i = 0; i < 8; ++i)
#pragma unroll
    for (int j = 0; j < 8; ++j) acc[i][j] = bj[j];

  for (int k0 = 0; k0 < Kd; k0 += BK) {
    float4 av = make_float4(0.f, 0.f, 0.f, 0.f);
    float4 wv = make_float4(0.f, 0.f, 0.f, 0.f);
    if (m0 + lm < M && k0 + lk < Kd)
      av = *(const float4*)(A + (size_t)(m0 + lm) * Kd + k0 + lk);
    if (n0 + lm < N && k0 + lk < Kd)
      wv = *(const float4*)(W + (size_t)(n0 + lm) * Kd + k0 + lk);
    __syncthreads();
    As[lk + 0][lm] = av.x; As[lk + 1][lm] = av.y;
    As[lk + 2][lm] = av.z; As[lk + 3][lm] = av.w;
    Ws[lk + 0][lm] = wv.x; Ws[lk + 1][lm] = wv.y;
    Ws[lk + 2][lm] = wv.z; Ws[lk + 3][lm] = wv.w;
    __syncthreads();
#pragma unroll
    for (int kk = 0; kk < BK; ++kk) {
      float a[8], w[8];
      *(float4*)&a[0] = *(const float4*)&As[kk][ty * 8];
      *(float4*)&a[4] = *(const float4*)&As[kk][ty * 8 + 4];
      *(float4*)&w[0] = *(const float4*)&Ws[kk][tx * 8];
      *(float4*)&w[4] = *(const float4*)&Ws[kk][tx * 8 + 4];
#pragma unroll
      for (int i = 0; i < 8; ++i)
#pragma unroll
        for (int j = 0; j < 8; ++j) acc[i][j] += a[i] * w[j];
    }
  }
#pragma unroll
  for (int i = 0; i < 8; ++i) {
    int m = m0 + ty * 8 + i;
    if (m < M) {
#pragma unroll
      for (int j0 = 0; j0 < 8; j0 += 4) {
        int n = n0 + tx * 8 + j0;
        if (n < N) {
          float4 o = make_float4(acc[i][j0], acc[i][j0 + 1], acc[i][j0 + 2], acc[i][j0 + 3]);
          *(float4*)(C + (size_t)m * N + n) = o;
        }
      }
    }
  }
}

// --------------------------- chunked LSTM ----------------------------------
// 256 blocks: [0,128)=fwd, [128,256)=bwd; each owns NB=4 batch elems for TC
// steps.  thread=(j 0..127, khalf); whh gate rows for j in 208 VGPRs; h
// broadcast from LDS.  h/c carried in ws between chunk launches.
__global__ __launch_bounds__(256, 1) void lstm_chunk(
    const float* __restrict__ XPf, const float* __restrict__ XPb,
    int xp_stride,
    const int* __restrict__ gather,  // sent (layer0) or nullptr (layer1)
    const float* __restrict__ whhF, const float* __restrict__ whhB,
    float* __restrict__ stateH, float* __restrict__ stateC,
    float* __restrict__ hout,
    int tbaseF, int tbaseB, int TC, int first, int B) {
  const int tid = threadIdx.x;
  const int j = tid & 127;
  const int kh = tid >> 7;
  const int dir = blockIdx.x >> 7;
  const int b0 = (blockIdx.x & 127) * NB;
  const float* __restrict__ XP = dir ? XPb : XPf;
  const float* __restrict__ whh = dir ? whhB : whhF;
  const int tbase = dir ? tbaseB : tbaseF;

  __shared__ float h_s[NB][104];       // k padded 100->104 (pad stays 0)
  __shared__ float red[4 * NB][129];   // khalf=1 partial sums

  float w[4][52];
#pragma unroll
  for (int r = 0; r < 4; ++r) {
#pragma unroll
    for (int kk = 0; kk < 52; ++kk) {
      int k = kh * 52 + kk;
      w[r][kk] = (j < 100 && k < 100) ? whh[(r * 100 + j) * 100 + k] : 0.f;
    }
  }
  for (int i = tid; i < NB * 104; i += 256) {
    int bb = i / 104, jj = i - bb * 104;
    float v = 0.f;
    if (!first && jj < 100)
      v = stateH[((size_t)dir * B + b0 + bb) * 100 + jj];
    ((float*)h_s)[i] = v;
  }
  const bool owner = (kh == 0) && (j < 100);
  float c[NB];
#pragma unroll
  for (int b = 0; b < NB; ++b)
    c[b] = (owner && !first) ? stateC[((size_t)dir * B + b0 + b) * 100 + j] : 0.f;
  __syncthreads();

  for (int s = 0; s < TC; ++s) {
    const int t = dir ? (tbase + TC - 1 - s) : (tbase + s);
    float xv[4][NB];
    if (owner) {
#pragma unroll
      for (int b = 0; b < NB; ++b) {
        size_t row = gather ? (size_t)gather[(size_t)t * B + b0 + b]
                            : ((size_t)(t - tbase) * B + b0 + b);
        const float* xb = XP + row * xp_stride;
#pragma unroll
        for (int r = 0; r < 4; ++r) xv[r][b] = xb[r * 100 + j];
      }
    }
    float acc[4][NB];
#pragma unroll
    for (int r = 0; r < 4; ++r)
#pragma unroll
      for (int b = 0; b < NB; ++b) acc[r][b] = 0.f;

#pragma unroll
    for (int q = 0; q < 13; ++q) {
#pragma unroll
      for (int b = 0; b < NB; ++b) {
        const float4 hb = *(const float4*)&h_s[b][kh * 52 + q * 4];
#pragma unroll
        for (int r = 0; r < 4; ++r) {
          acc[r][b] += w[r][q * 4 + 0] * hb.x + w[r][q * 4 + 1] * hb.y +
                       w[r][q * 4 + 2] * hb.z + w[r][q * 4 + 3] * hb.w;
        }
      }
    }
    if (kh == 1) {
#pragma unroll
      for (int r = 0; r < 4; ++r)
#pragma unroll
        for (int b = 0; b < NB; ++b) red[r * NB + b][j] = acc[r][b];
    }
    __syncthreads();
    if (owner) {
#pragma unroll
      for (int b = 0; b < NB; ++b) {
        float gi = acc[0][b] + red[0 * NB + b][j] + xv[0][b];
        float gf = acc[1][b] + red[1 * NB + b][j] + xv[1][b];
        float gg = acc[2][b] + red[2 * NB + b][j] + xv[2][b];
        float go = acc[3][b] + red[3 * NB + b][j] + xv[3][b];
        float i_ = sigm(gi), f_ = sigm(gf);
        float g_ = tanh_f(gg), o_ = sigm(go);
        float cn = f_ * c[b] + i_ * g_;
        c[b] = cn;
        float hn = o_ * tanh_f(cn);
        h_s[b][j] = hn;
        hout[((size_t)t * B + b0 + b) * 200 + dir * 100 + j] = hn;
      }
    }
    __syncthreads();
  }
  if (owner) {
#pragma unroll
    for (int b = 0; b < NB; ++b) {
      stateH[((size_t)dir * B + b0 + b) * 100 + j] = h_s[b][j];
      stateC[((size_t)dir * B + b0 + b) * 100 + j] = c[b];
    }
  }
}

// --------------------------- emission kernel -------------------------------
__global__ __launch_bounds__(256) void em_kernel(
    const float* __restrict__ h2, const float* __restrict__ wl,
    const float* __restrict__ bl_, float* __restrict__ em) {
  __shared__ float hsb[32][200];
  __shared__ float wls[8 * 200];
  __shared__ float bls[8];
  const int tid = threadIdx.x;
  const int row0 = blockIdx.x * 32;
  for (int i = tid; i < 1600; i += 256) wls[i] = wl[i];
  if (tid < 8) bls[tid] = bl_[tid];
  for (int i = tid; i < 1600; i += 256) {
    int r = i / 50, q = i - r * 50;
    *(float4*)&hsb[r][q * 4] = *(const float4*)(h2 + (size_t)(row0 + r) * 200 + q * 4);
  }
  __syncthreads();
  const int r_l = tid >> 3, k = tid & 7;
  float acc = bls[k];
#pragma unroll
  for (int d4 = 0; d4 < 50; ++d4) {
    float4 h = *(const float4*)&hsb[r_l][d4 * 4];
    float4 wv = *(const float4*)&wls[k * 200 + d4 * 4];
    acc += h.x * wv.x + h.y * wv.y + h.z * wv.z + h.w * wv.w;
  }
  em[(size_t)(row0 + r_l) * 8 + k] = acc;
}

// --------------------------- CRF loss kernel -------------------------------
__global__ __launch_bounds__(256) void crf_kernel(
    const float* __restrict__ em, const int* __restrict__ tags,
    const float* __restrict__ start_t, const float* __restrict__ end_t,
    const float* __restrict__ trans, float* __restrict__ loss_out,
    int T, int B) {
  const int tid = threadIdx.x;
  const int bl = tid >> 3, jj = tid & 7;
  const int b = blockIdx.x * 32 + bl;
  __shared__ float sc[2][32][9];
  __shared__ float rednum[32][8];
  __shared__ float partial[32];
  float trj[8];
#pragma unroll
  for (int i = 0; i < 8; ++i) trj[i] = trans[i * 8 + jj];

  float pnum = 0.f;
  for (int t = 1 + jj; t < T; t += 8) {
    int tp = tags[(size_t)(t - 1) * B + b];
    int tc = tags[(size_t)t * B + b];
    pnum += trans[tp * 8 + tc] + em[((size_t)t * B + b) * 8 + tc];
  }
  rednum[bl][jj] = pnum;
  __syncthreads();
  float num = 0.f;
  if (jj == 0) {
#pragma unroll
    for (int i = 0; i < 8; ++i) num += rednum[bl][i];
    int t0 = tags[b];
    int tl = tags[(size_t)(T - 1) * B + b];
    num += start_t[t0] + em[(size_t)b * 8 + t0] + end_t[tl];
  }
  sc[0][bl][jj] = start_t[jj] + em[(size_t)b * 8 + jj];
  __syncthreads();
  for (int t = 1; t < T; ++t) {
    int cur = t & 1, prev = cur ^ 1;
    float m = -1e30f;
    float v[8];
#pragma unroll
    for (int i = 0; i < 8; ++i) {
      v[i] = sc[prev][bl][i] + trj[i];
      m = fmaxf(m, v[i]);
    }
    float ssum = 0.f;
#pragma unroll
    for (int i = 0; i < 8; ++i) ssum += __expf(v[i] - m);
    sc[cur][bl][jj] = m + __logf(ssum) + em[((size_t)t * B + b) * 8 + jj];
    __syncthreads();
  }
  rednum[bl][jj] = sc[(T - 1) & 1][bl][jj] + end_t[jj];
  __syncthreads();
  if (jj == 0) {
    float m = -1e30f;
#pragma unroll
    for (int i = 0; i < 8; ++i) m = fmaxf(m, rednum[bl][i]);
    float ssum = 0.f;
#pragma unroll
    for (int i = 0; i < 8; ++i) ssum += __expf(rednum[bl][i] - m);
    partial[bl] = num - (m + __logf(ssum));
  }
  __syncthreads();
  if (tid == 0) {
    float s2 = 0.f;
#pragma unroll
    for (int i = 0; i < 32; ++i) s2 += partial[i];
    atomicAdd(loss_out, s2);
  }
}

// --------------------------- Viterbi kernel --------------------------------
__global__ __launch_bounds__(256) void viterbi_kernel(
    const float* __restrict__ em, const float* __restrict__ start_t,
    const float* __restrict__ end_t, const float* __restrict__ trans,
    float* __restrict__ dec_out, int T, int B) {
  const int tid = threadIdx.x;
  const int bl = tid >> 3, jj = tid & 7;
  const int b = blockIdx.x * 32 + bl;
  __shared__ float sc[2][32][9];
  __shared__ unsigned hist[T_LEN - 1][32];  // 3 bits per state
  __shared__ float redm[32][8];
  __shared__ int lastt[32];
  float trj[8];
#pragma unroll
  for (int i = 0; i < 8; ++i) trj[i] = trans[i * 8 + jj];
  for (int i = tid; i < (T_LEN - 1) * 32; i += 256) ((unsigned*)hist)[i] = 0u;
  sc[0][bl][jj] = start_t[jj] + em[(size_t)b * 8 + jj];
  __syncthreads();
  for (int t = 1; t < T; ++t) {
    int cur = t & 1, prev = cur ^ 1;
    float m = -1e30f;
    int am = 0;
#pragma unroll
    for (int i = 0; i < 8; ++i) {
      float v = sc[prev][bl][i] + trj[i];
      if (v > m) { m = v; am = i; }   // strict > keeps first (jnp.argmax)
    }
    atomicOr(&hist[t - 1][bl], (unsigned)am << (3 * jj));
    sc[cur][bl][jj] = m + em[((size_t)t * B + b) * 8 + jj];
    __syncthreads();
  }
  redm[bl][jj] = sc[(T - 1) & 1][bl][jj] + end_t[jj];
  __syncthreads();
  if (jj == 0) {
    float m = -1e30f;
    int am = 0;
#pragma unroll
    for (int i = 0; i < 8; ++i) {
      float v = redm[bl][i];
      if (v > m) { m = v; am = i; }
    }
    lastt[bl] = am;
  }
  __syncthreads();
  if (tid < 32) {
    int bb = blockIdx.x * 32 + tid;
    int cur = lastt[tid];
    dec_out[(size_t)(T - 1) * B + bb] = (float)cur;
    for (int t2 = T - 2; t2 >= 0; --t2) {
      cur = (int)((hist[t2][tid] >> (3 * cur)) & 7u);
      dec_out[(size_t)t2 * B + bb] = (float)cur;
    }
  }
}

// --------------------------- ws-too-small reporter -------------------------
__global__ __launch_bounds__(256) void report_kernel(float* out, float wsval, int n) {
  int i = blockIdx.x * blockDim.x + threadIdx.x;
  if (i == 0) out[0] = wsval;
  else if (i < n) out[i] = 0.f;
}

// --------------------------- launch ----------------------------------------
extern "C" void kernel_launch(void* const* d_in, const int* in_sizes, int n_in,
                              void* d_out, int out_size, void* d_ws, size_t ws_size,
                              hipStream_t stream) {
  const int* sentence = (const int*)d_in[0];
  const int* tags     = (const int*)d_in[1];
  const float* emb   = (const float*)d_in[3];
  const float* wih0f = (const float*)d_in[4];
  const float* whh0f = (const float*)d_in[5];
  const float* bih0f = (const float*)d_in[6];
  const float* bhh0f = (const float*)d_in[7];
  const float* wih0b = (const float*)d_in[8];
  const float* whh0b = (const float*)d_in[9];
  const float* bih0b = (const float*)d_in[10];
  const float* bhh0b = (const float*)d_in[11];
  const float* wih1f = (const float*)d_in[12];
  const float* whh1f = (const float*)d_in[13];
  const float* bih1f = (const float*)d_in[14];
  const float* bhh1f = (const float*)d_in[15];
  const float* wih1b = (const float*)d_in[16];
  const float* whh1b = (const float*)d_in[17];
  const float* bih1b = (const float*)d_in[18];
  const float* bhh1b = (const float*)d_in[19];
  const float* wl      = (const float*)d_in[20];
  const float* bl_     = (const float*)d_in[21];
  const float* start_t = (const float*)d_in[22];
  const float* end_t   = (const float*)d_in[23];
  const float* trans   = (const float*)d_in[24];

  const int T = T_LEN, B = B_SZ;
  float* out = (float*)d_out;
  float* ws = (float*)d_ws;

  // ---- workspace layout (float offsets); ws is 256 MiB = 67,108,864 fl ----
  const size_t O_P0  = 0;            // 40,000,000
  const size_t O_H1  = 40000000ull;  // 26,214,400 -> ends 66,214,400
  const size_t O_W0  = 66214400ull;  // 240,000 (+B0 800) -> 66,455,200
  const size_t O_B0  = 66454400ull;
  const size_t O_STH = 66214400ull;  // aliases W0 (dead after vocab gemm)
  const size_t O_STC = 66316800ull;
  const size_t O_W1  = 66455200ull;  // 160,000 (+B1 800) -> 66,616,000
  const size_t O_B1  = 66615200ull;
  const size_t TOTAL_FL = 66616000ull;
  // P0-region aliases (valid once P0 is dead, i.e. after lstm0):
  const size_t O_H2  = 0;            // 26,214,400
  const size_t O_XPF = 26214400ull;  // 6,553,600
  const size_t O_XPB = 32768000ull;  // 6,553,600 -> ends 39,321,600 <= 40M
  const size_t O_EM  = 26214400ull;  // 1,048,576 (after layer1; XP dead)

  if (ws_size < TOTAL_FL * 4ull) {
    report_kernel<<<(out_size + 255) / 256, 256, 0, stream>>>(out, (float)ws_size, out_size);
    return;
  }

  float* P0  = ws + O_P0;
  float* h1  = ws + O_H1;
  float* W0  = ws + O_W0;
  float* B0  = ws + O_B0;
  float* stH = ws + O_STH;
  float* stC = ws + O_STC;
  float* W1  = ws + O_W1;
  float* B1  = ws + O_B1;
  float* h2  = ws + O_H2;
  float* XPF = ws + O_XPF;
  float* XPB = ws + O_XPB;
  float* em  = ws + O_EM;

  pack_kernel<<<256, 256, 0, stream>>>(wih0f, bih0f, bhh0f, wih0b, bih0b, bhh0b,
                                       wih1f, bih1f, bhh1f, wih1b, bih1b, bhh1b,
                                       W0, B0, W1, B1, out);
  // vocab projection: P0[50000][800]
  dim3 g1((50000 + BM - 1) / BM, (800 + BN - 1) / BN);
  gemm_tn<<<g1, 256, 0, stream>>>(emb, W0, B0, P0, 50000, 800, 300);

  // layer 0: persistent single launch, both dirs, gather via sentence.
  // (writes stH/stC at end -> aliases dead W0; harmless)
  lstm_chunk<<<256, 256, 0, stream>>>(P0, P0 + 400, 800, sentence, whh0f, whh0b,
                                      stH, stC, h1, 0, 0, T, 1, B);

  // layer 1: chunked (fwd ascending, bwd descending); XP/h2 recycle P0 space
  dim3 gc((TCH * B + BM - 1) / BM, (400 + BN - 1) / BN);
  for (int cc = 0; cc < T / TCH; ++cc) {
    int baseF = cc * TCH;
    int baseB = T - TCH - cc * TCH;
    gemm_tn<<<gc, 256, 0, stream>>>(h1 + (size_t)baseF * B * 200, W1, B1,
                                    XPF, TCH * B, 400, 200);
    gemm_tn<<<gc, 256, 0, stream>>>(h1 + (size_t)baseB * B * 200, W1 + 80000, B1 + 400,
                                    XPB, TCH * B, 400, 200);
    lstm_chunk<<<256, 256, 0, stream>>>(XPF, XPB, 400, nullptr, whh1f, whh1b,
                                        stH, stC, h2, baseF, baseB, TCH, cc == 0, B);
  }

  em_kernel<<<(T * B) / 32, 256, 0, stream>>>(h2, wl, bl_, em);
  crf_kernel<<<B / 32, 256, 0, stream>>>(em, tags, start_t, end_t, trans, out, T, B);
  viterbi_kernel<<<B / 32, 256, 0, stream>>>(em, start_t, end_t, trans, out + 1, T, B);
}

// Round 4
// 2593.378 us; speedup vs baseline: 1.5803x; 1.5803x over previous
//
#include <hip/hip_runtime.h>
#include <math.h>

// ---------------------------------------------------------------------------
// BiLSTM(2 layers) + CRF NER.  T=256 B=512 V=50000 E=300 H=100 K=8
// All fp32 (no fp32 MFMA; bf16 would risk Viterbi argmax flips).
// R4: lstm2 rewrite — gate-split lanes (w in 200 VGPRs, no spill), shfl gate
// exchange, 1 barrier/step, x prefetch, 512 blocks (2/CU).  GEMM: global
// prefetch; dual-dir chunk GEMM in one launch.  CRF/Viterbi: 64 blocks.
// ws = 256 MiB measured (R2).  Layout (float offsets), total 66,616,000 fl:
//   [0, 40,000,000)          P0[50000][800]; recycled after lstm0:
//         h2 @0 [26,214,400], XPF @26,214,400, XPB @32,768,000,
//         em @26,214,400 (after layer1)
//   [40,000,000, 66,214,400) h1
//   [66,214,400, ...)        W0+B0 (dead after vocab gemm; stH/stC alias)
//   [66,455,200, 66,616,000) W1+B1
// ---------------------------------------------------------------------------

#define T_LEN 256
#define B_SZ  512
#define TCH   32

__device__ __forceinline__ float sigm(float x) { return 1.f / (1.f + __expf(-x)); }
__device__ __forceinline__ float tanh_f(float x) {
  float e = __expf(-2.f * fabsf(x));
  float r = (1.f - e) / (1.f + e);
  return copysignf(r, x);
}

// --------------------------- pack kernel -----------------------------------
__global__ __launch_bounds__(256) void pack_kernel(
    const float* __restrict__ wih0f, const float* __restrict__ bih0f, const float* __restrict__ bhh0f,
    const float* __restrict__ wih0b, const float* __restrict__ bih0b, const float* __restrict__ bhh0b,
    const float* __restrict__ wih1f, const float* __restrict__ bih1f, const float* __restrict__ bhh1f,
    const float* __restrict__ wih1b, const float* __restrict__ bih1b, const float* __restrict__ bhh1b,
    float* __restrict__ W0, float* __restrict__ B0,
    float* __restrict__ W1, float* __restrict__ B1,
    float* __restrict__ out0) {
  int idx = blockIdx.x * blockDim.x + threadIdx.x;
  int stride = gridDim.x * blockDim.x;
  if (idx == 0) out0[0] = 0.f;
  for (int i = idx; i < 800 * 300; i += stride) {
    int g = i / 300, d = i - g * 300;
    W0[i] = (g < 400) ? wih0f[g * 300 + d] : wih0b[(g - 400) * 300 + d];
  }
  for (int i = idx; i < 800 * 200; i += stride) {
    int g = i / 200, d = i - g * 200;
    W1[i] = (g < 400) ? wih1f[g * 200 + d] : wih1b[(g - 400) * 200 + d];
  }
  for (int i = idx; i < 800; i += stride) {
    B0[i] = (i < 400) ? (bih0f[i] + bhh0f[i]) : (bih0b[i - 400] + bhh0b[i - 400]);
    B1[i] = (i < 400) ? (bih1f[i] + bhh1f[i]) : (bih1b[i - 400] + bhh1b[i - 400]);
  }
}

// --------------------------- fp32 GEMM body --------------------------------
// C[M][N] = A[M][Kd] . W[N][Kd]^T + bias[N].  128x128 tile, 8x8 micro, BK=8,
// global->reg prefetch so vmcnt latency overlaps the FMA loop.
#define BM 128
#define BN 128
#define BK 8
__device__ __forceinline__ void gemm_body(
    const float* __restrict__ A, const float* __restrict__ W,
    const float* __restrict__ bias, float* __restrict__ C,
    int M, int N, int Kd, int m0, int n0,
    float (*As)[BM], float (*Ws)[BN]) {
  const int tid = threadIdx.x;
  const int tx = tid & 15, ty = tid >> 4;
  const int lm = tid >> 1;
  const int lk = (tid & 1) * 4;

  float acc[8][8];
  float bj[8];
#pragma unroll
  for (int j = 0; j < 8; ++j) {
    int n = n0 + tx * 8 + j;
    bj[j] = (n < N) ? bias[n] : 0.f;
  }
#pragma unroll
  for (int i = 0; i < 8; ++i)
#pragma unroll
    for (int j = 0; j < 8; ++j) acc[i][j] = bj[j];

  // prologue prefetch for k0 = 0
  float4 av = make_float4(0.f, 0.f, 0.f, 0.f);
  float4 wv = make_float4(0.f, 0.f, 0.f, 0.f);
  if (m0 + lm < M && lk < Kd)
    av = *(const float4*)(A + (size_t)(m0 + lm) * Kd + lk);
  if (n0 + lm < N && lk < Kd)
    wv = *(const float4*)(W + (size_t)(n0 + lm) * Kd + lk);

  for (int k0 = 0; k0 < Kd; k0 += BK) {
    __syncthreads();
    As[lk + 0][lm] = av.x; As[lk + 1][lm] = av.y;
    As[lk + 2][lm] = av.z; As[lk + 3][lm] = av.w;
    Ws[lk + 0][lm] = wv.x; Ws[lk + 1][lm] = wv.y;
    Ws[lk + 2][lm] = wv.z; Ws[lk + 3][lm] = wv.w;
    __syncthreads();
    // prefetch next k-tile while computing this one
    int k0n = k0 + BK;
    av = make_float4(0.f, 0.f, 0.f, 0.f);
    wv = make_float4(0.f, 0.f, 0.f, 0.f);
    if (k0n < Kd) {
      if (m0 + lm < M && k0n + lk < Kd)
        av = *(const float4*)(A + (size_t)(m0 + lm) * Kd + k0n + lk);
      if (n0 + lm < N && k0n + lk < Kd)
        wv = *(const float4*)(W + (size_t)(n0 + lm) * Kd + k0n + lk);
    }
#pragma unroll
    for (int kk = 0; kk < BK; ++kk) {
      float a[8], w[8];
      *(float4*)&a[0] = *(const float4*)&As[kk][ty * 8];
      *(float4*)&a[4] = *(const float4*)&As[kk][ty * 8 + 4];
      *(float4*)&w[0] = *(const float4*)&Ws[kk][tx * 8];
      *(float4*)&w[4] = *(const float4*)&Ws[kk][tx * 8 + 4];
#pragma unroll
      for (int i = 0; i < 8; ++i)
#pragma unroll
        for (int j = 0; j < 8; ++j) acc[i][j] += a[i] * w[j];
    }
  }
#pragma unroll
  for (int i = 0; i < 8; ++i) {
    int m = m0 + ty * 8 + i;
    if (m < M) {
#pragma unroll
      for (int j0 = 0; j0 < 8; j0 += 4) {
        int n = n0 + tx * 8 + j0;
        if (n < N) {
          float4 o = make_float4(acc[i][j0], acc[i][j0 + 1], acc[i][j0 + 2], acc[i][j0 + 3]);
          *(float4*)(C + (size_t)m * N + n) = o;
        }
      }
    }
  }
}

__global__ __launch_bounds__(256, 2) void gemm_tn(
    const float* __restrict__ A, const float* __restrict__ W,
    const float* __restrict__ bias, float* __restrict__ C,
    int M, int N, int Kd) {
  __shared__ float As[BK][BM];
  __shared__ float Ws[BK][BN];
  gemm_body(A, W, bias, C, M, N, Kd, blockIdx.x * BM, blockIdx.y * BN, As, Ws);
}

// dual-direction chunk GEMM: z=0 fwd (rows baseF, W1 half 0 -> XPF),
// z=1 bwd (rows baseB, W1 half 1 -> XPB)
__global__ __launch_bounds__(256, 2) void gemm_dual(
    const float* __restrict__ h1, const float* __restrict__ W1,
    const float* __restrict__ B1, float* __restrict__ XPF,
    float* __restrict__ XPB, int baseF, int baseB, int B) {
  __shared__ float As[BK][BM];
  __shared__ float Ws[BK][BN];
  const int dir = blockIdx.z;
  const float* A = h1 + (size_t)(dir ? baseB : baseF) * B * 200;
  const float* W = W1 + (size_t)dir * 80000;
  const float* bias = B1 + dir * 400;
  float* C = dir ? XPB : XPF;
  gemm_body(A, W, bias, C, TCH * B, 400, 200, blockIdx.x * BM, blockIdx.y * BN, As, Ws);
}

// --------------------------- LSTM v2 ---------------------------------------
// 512 blocks (2/CU): [0,256)=fwd, [256,512)=bwd; each block owns 2 batch
// elems.  Lane pair (2j, 2j+1): gp=0 holds gate rows {i,f} of output j with
// full K=100 in 200 VGPRs; gp=1 holds {g,o}.  Gate exchange via shfl_xor(1).
// h double-buffered in LDS -> 1 barrier/step.  x and sent prefetched.
__global__ __launch_bounds__(256, 2) void lstm2(
    const float* __restrict__ XPf, const float* __restrict__ XPb,
    int xp_stride,
    const int* __restrict__ gather,  // sent (layer0) or nullptr (layer1)
    const float* __restrict__ whhF, const float* __restrict__ whhB,
    float* __restrict__ stateH, float* __restrict__ stateC,
    float* __restrict__ hout,
    int tbaseF, int tbaseB, int TC, int first, int B) {
  const int tid = threadIdx.x;
  const int j = tid >> 1;
  const int gp = tid & 1;
  const bool act = (j < 100);
  const int bpd = B >> 1;
  const int dir = (blockIdx.x >= (unsigned)bpd) ? 1 : 0;
  const int b0 = (dir ? (blockIdx.x - bpd) : blockIdx.x) * 2;
  const float* __restrict__ XP = dir ? XPb : XPf;
  const float* __restrict__ whh = dir ? whhB : whhF;
  const int tbase = dir ? tbaseB : tbaseF;
  const int tstep = dir ? -1 : 1;
  const int tfirst = dir ? (tbase + TC - 1) : tbase;
  const int cg0 = gp * 200 + j;     // col of first owned gate (i or g)
  const int cg1 = cg0 + 100;        // col of second owned gate (f or o)

  __shared__ float h_s[2][2][100];

  // weights: rows (2gp)*100+j and (2gp+1)*100+j, full K -> 200 VGPRs
  float4 w0[25], w1[25];
  {
    const float* p0 = whh + (size_t)(2 * gp) * 10000 + (size_t)j * 100;
    if (act) {
#pragma unroll
      for (int q = 0; q < 25; ++q) {
        w0[q] = *(const float4*)(p0 + q * 4);
        w1[q] = *(const float4*)(p0 + 10000 + q * 4);
      }
    } else {
#pragma unroll
      for (int q = 0; q < 25; ++q) {
        w0[q] = make_float4(0.f, 0.f, 0.f, 0.f);
        w1[q] = make_float4(0.f, 0.f, 0.f, 0.f);
      }
    }
  }

  float c0v = 0.f, c1v = 0.f;
  if (gp == 0 && act) {
    if (!first) {
      c0v = stateC[((size_t)dir * B + b0 + 0) * 100 + j];
      c1v = stateC[((size_t)dir * B + b0 + 1) * 100 + j];
      h_s[0][0][j] = stateH[((size_t)dir * B + b0 + 0) * 100 + j];
      h_s[0][1][j] = stateH[((size_t)dir * B + b0 + 1) * 100 + j];
    } else {
      h_s[0][0][j] = 0.f;
      h_s[0][1][j] = 0.f;
    }
  }

  // row-base helper (gather for layer0, direct for layer1)
  auto rowptr = [&](int tt, int bb) -> const float* {
    size_t r = gather ? (size_t)gather[(size_t)tt * B + b0 + bb]
                      : (size_t)(tt - tbase) * B + b0 + bb;
    return XP + r * (size_t)xp_stride;
  };

  // prologue: x for first step; row bases for second step
  float x00 = 0.f, x01 = 0.f, x10 = 0.f, x11 = 0.f;
  {
    const float* r0 = rowptr(tfirst, 0);
    const float* r1 = rowptr(tfirst, 1);
    if (act) { x00 = r0[cg0]; x10 = r0[cg1]; x01 = r1[cg0]; x11 = r1[cg1]; }
  }
  const float* baseN0 = XP;
  const float* baseN1 = XP;
  if (TC > 1) { baseN0 = rowptr(tfirst + tstep, 0); baseN1 = rowptr(tfirst + tstep, 1); }

  __syncthreads();

  int cur = 0;
  for (int s = 0; s < TC; ++s) {
    const int t = tfirst + s * tstep;
    // prefetch next-step x (rows known ahead of recurrence)
    float nx00 = 0.f, nx01 = 0.f, nx10 = 0.f, nx11 = 0.f;
    if (act && s + 1 < TC) {
      nx00 = baseN0[cg0]; nx10 = baseN0[cg1];
      nx01 = baseN1[cg0]; nx11 = baseN1[cg1];
    }
    // prefetch row bases (sent load) for step s+2
    if (s + 2 < TC) {
      baseN0 = rowptr(t + 2 * tstep, 0);
      baseN1 = rowptr(t + 2 * tstep, 1);
    }
    // recurrent matvec: 2 gates x 2 batch, full K from LDS broadcast
    float a00 = 0.f, a01 = 0.f, a10 = 0.f, a11 = 0.f;
    const float* hb0 = h_s[cur][0];
    const float* hb1 = h_s[cur][1];
#pragma unroll
    for (int q = 0; q < 25; ++q) {
      float4 h0 = *(const float4*)(hb0 + q * 4);
      float4 h1v = *(const float4*)(hb1 + q * 4);
      float4 W0q = w0[q], W1q = w1[q];
      a00 += W0q.x * h0.x + W0q.y * h0.y + W0q.z * h0.z + W0q.w * h0.w;
      a10 += W1q.x * h0.x + W1q.y * h0.y + W1q.z * h0.z + W1q.w * h0.w;
      a01 += W0q.x * h1v.x + W0q.y * h1v.y + W0q.z * h1v.z + W0q.w * h1v.w;
      a11 += W1q.x * h1v.x + W1q.y * h1v.y + W1q.z * h1v.z + W1q.w * h1v.w;
    }
    a00 += x00; a10 += x10; a01 += x01; a11 += x11;
    // exchange: gp=0 has (i,f) in (a0*,a1*); gp=1 has (g,o)
    float g0 = __shfl_xor(a00, 1);
    float g1 = __shfl_xor(a01, 1);
    float o0 = __shfl_xor(a10, 1);
    float o1 = __shfl_xor(a11, 1);
    const int nxt = cur ^ 1;
    if (gp == 0 && act) {
      float i0 = sigm(a00), f0 = sigm(a10);
      c0v = f0 * c0v + i0 * tanh_f(g0);
      float h0n = sigm(o0) * tanh_f(c0v);
      float i1 = sigm(a01), f1 = sigm(a11);
      c1v = f1 * c1v + i1 * tanh_f(g1);
      float h1n = sigm(o1) * tanh_f(c1v);
      h_s[nxt][0][j] = h0n;
      h_s[nxt][1][j] = h1n;
      hout[((size_t)t * B + b0 + 0) * 200 + dir * 100 + j] = h0n;
      hout[((size_t)t * B + b0 + 1) * 200 + dir * 100 + j] = h1n;
    }
    __syncthreads();
    cur = nxt;
    x00 = nx00; x01 = nx01; x10 = nx10; x11 = nx11;
  }
  if (gp == 0 && act) {
    stateH[((size_t)dir * B + b0 + 0) * 100 + j] = h_s[cur][0][j];
    stateH[((size_t)dir * B + b0 + 1) * 100 + j] = h_s[cur][1][j];
    stateC[((size_t)dir * B + b0 + 0) * 100 + j] = c0v;
    stateC[((size_t)dir * B + b0 + 1) * 100 + j] = c1v;
  }
}

// --------------------------- emission kernel -------------------------------
__global__ __launch_bounds__(256) void em_kernel(
    const float* __restrict__ h2, const float* __restrict__ wl,
    const float* __restrict__ bl_, float* __restrict__ em) {
  __shared__ float hsb[32][200];
  __shared__ float wls[8 * 200];
  __shared__ float bls[8];
  const int tid = threadIdx.x;
  const int row0 = blockIdx.x * 32;
  for (int i = tid; i < 1600; i += 256) wls[i] = wl[i];
  if (tid < 8) bls[tid] = bl_[tid];
  for (int i = tid; i < 1600; i += 256) {
    int r = i / 50, q = i - r * 50;
    *(float4*)&hsb[r][q * 4] = *(const float4*)(h2 + (size_t)(row0 + r) * 200 + q * 4);
  }
  __syncthreads();
  const int r_l = tid >> 3, k = tid & 7;
  float acc = bls[k];
#pragma unroll
  for (int d4 = 0; d4 < 50; ++d4) {
    float4 h = *(const float4*)&hsb[r_l][d4 * 4];
    float4 wv = *(const float4*)&wls[k * 200 + d4 * 4];
    acc += h.x * wv.x + h.y * wv.y + h.z * wv.z + h.w * wv.w;
  }
  em[(size_t)(row0 + r_l) * 8 + k] = acc;
}

// --------------------------- CRF loss kernel (8 seqs/block) ----------------
__global__ __launch_bounds__(64) void crf_kernel(
    const float* __restrict__ em, const int* __restrict__ tags,
    const float* __restrict__ start_t, const float* __restrict__ end_t,
    const float* __restrict__ trans, float* __restrict__ loss_out,
    int T, int B) {
  const int tid = threadIdx.x;
  const int bl = tid >> 3, jj = tid & 7;
  const int b = blockIdx.x * 8 + bl;
  __shared__ float sc[2][8][9];
  __shared__ float rednum[8][8];
  __shared__ float partial[8];
  float trj[8];
#pragma unroll
  for (int i = 0; i < 8; ++i) trj[i] = trans[i * 8 + jj];

  float pnum = 0.f;
  for (int t = 1 + jj; t < T; t += 8) {
    int tp = tags[(size_t)(t - 1) * B + b];
    int tc = tags[(size_t)t * B + b];
    pnum += trans[tp * 8 + tc] + em[((size_t)t * B + b) * 8 + tc];
  }
  rednum[bl][jj] = pnum;
  __syncthreads();
  float num = 0.f;
  if (jj == 0) {
#pragma unroll
    for (int i = 0; i < 8; ++i) num += rednum[bl][i];
    int t0 = tags[b];
    int tl = tags[(size_t)(T - 1) * B + b];
    num += start_t[t0] + em[(size_t)b * 8 + t0] + end_t[tl];
  }
  sc[0][bl][jj] = start_t[jj] + em[(size_t)b * 8 + jj];
  __syncthreads();
  for (int t = 1; t < T; ++t) {
    int cur = t & 1, prev = cur ^ 1;
    float m = -1e30f;
    float v[8];
#pragma unroll
    for (int i = 0; i < 8; ++i) {
      v[i] = sc[prev][bl][i] + trj[i];
      m = fmaxf(m, v[i]);
    }
    float ssum = 0.f;
#pragma unroll
    for (int i = 0; i < 8; ++i) ssum += __expf(v[i] - m);
    sc[cur][bl][jj] = m + __logf(ssum) + em[((size_t)t * B + b) * 8 + jj];
    __syncthreads();
  }
  rednum[bl][jj] = sc[(T - 1) & 1][bl][jj] + end_t[jj];
  __syncthreads();
  if (jj == 0) {
    float m = -1e30f;
#pragma unroll
    for (int i = 0; i < 8; ++i) m = fmaxf(m, rednum[bl][i]);
    float ssum = 0.f;
#pragma unroll
    for (int i = 0; i < 8; ++i) ssum += __expf(rednum[bl][i] - m);
    partial[bl] = num - (m + __logf(ssum));
  }
  __syncthreads();
  if (tid == 0) {
    float s2 = 0.f;
#pragma unroll
    for (int i = 0; i < 8; ++i) s2 += partial[i];
    atomicAdd(loss_out, s2);
  }
}

// --------------------------- Viterbi kernel (8 seqs/block) -----------------
__global__ __launch_bounds__(64) void viterbi_kernel(
    const float* __restrict__ em, const float* __restrict__ start_t,
    const float* __restrict__ end_t, const float* __restrict__ trans,
    float* __restrict__ dec_out, int T, int B) {
  const int tid = threadIdx.x;
  const int bl = tid >> 3, jj = tid & 7;
  const int b = blockIdx.x * 8 + bl;
  __shared__ float sc[2][8][9];
  __shared__ unsigned hist[T_LEN - 1][8];  // 3 bits per state
  __shared__ float redm[8][8];
  __shared__ int lastt[8];
  float trj[8];
#pragma unroll
  for (int i = 0; i < 8; ++i) trj[i] = trans[i * 8 + jj];
  for (int i = tid; i < (T_LEN - 1) * 8; i += 64) ((unsigned*)hist)[i] = 0u;
  sc[0][bl][jj] = start_t[jj] + em[(size_t)b * 8 + jj];
  __syncthreads();
  for (int t = 1; t < T; ++t) {
    int cur = t & 1, prev = cur ^ 1;
    float m = -1e30f;
    int am = 0;
#pragma unroll
    for (int i = 0; i < 8; ++i) {
      float v = sc[prev][bl][i] + trj[i];
      if (v > m) { m = v; am = i; }   // strict > keeps first (jnp.argmax)
    }
    atomicOr(&hist[t - 1][bl], (unsigned)am << (3 * jj));
    sc[cur][bl][jj] = m + em[((size_t)t * B + b) * 8 + jj];
    __syncthreads();
  }
  redm[bl][jj] = sc[(T - 1) & 1][bl][jj] + end_t[jj];
  __syncthreads();
  if (jj == 0) {
    float m = -1e30f;
    int am = 0;
#pragma unroll
    for (int i = 0; i < 8; ++i) {
      float v = redm[bl][i];
      if (v > m) { m = v; am = i; }
    }
    lastt[bl] = am;
  }
  __syncthreads();
  if (tid < 8) {
    int bb = blockIdx.x * 8 + tid;
    int cur = lastt[tid];
    dec_out[(size_t)(T - 1) * B + bb] = (float)cur;
    for (int t2 = T - 2; t2 >= 0; --t2) {
      cur = (int)((hist[t2][tid] >> (3 * cur)) & 7u);
      dec_out[(size_t)t2 * B + bb] = (float)cur;
    }
  }
}

// --------------------------- ws-too-small reporter -------------------------
__global__ __launch_bounds__(256) void report_kernel(float* out, float wsval, int n) {
  int i = blockIdx.x * blockDim.x + threadIdx.x;
  if (i == 0) out[0] = wsval;
  else if (i < n) out[i] = 0.f;
}

// --------------------------- launch ----------------------------------------
extern "C" void kernel_launch(void* const* d_in, const int* in_sizes, int n_in,
                              void* d_out, int out_size, void* d_ws, size_t ws_size,
                              hipStream_t stream) {
  const int* sentence = (const int*)d_in[0];
  const int* tags     = (const int*)d_in[1];
  const float* emb   = (const float*)d_in[3];
  const float* wih0f = (const float*)d_in[4];
  const float* whh0f = (const float*)d_in[5];
  const float* bih0f = (const float*)d_in[6];
  const float* bhh0f = (const float*)d_in[7];
  const float* wih0b = (const float*)d_in[8];
  const float* whh0b = (const float*)d_in[9];
  const float* bih0b = (const float*)d_in[10];
  const float* bhh0b = (const float*)d_in[11];
  const float* wih1f = (const float*)d_in[12];
  const float* whh1f = (const float*)d_in[13];
  const float* bih1f = (const float*)d_in[14];
  const float* bhh1f = (const float*)d_in[15];
  const float* wih1b = (const float*)d_in[16];
  const float* whh1b = (const float*)d_in[17];
  const float* bih1b = (const float*)d_in[18];
  const float* bhh1b = (const float*)d_in[19];
  const float* wl      = (const float*)d_in[20];
  const float* bl_     = (const float*)d_in[21];
  const float* start_t = (const float*)d_in[22];
  const float* end_t   = (const float*)d_in[23];
  const float* trans   = (const float*)d_in[24];

  const int T = T_LEN, B = B_SZ;
  float* out = (float*)d_out;
  float* ws = (float*)d_ws;

  // ---- workspace layout (float offsets); ws is 256 MiB = 67,108,864 fl ----
  const size_t O_P0  = 0;            // 40,000,000
  const size_t O_H1  = 40000000ull;  // 26,214,400 -> ends 66,214,400
  const size_t O_W0  = 66214400ull;  // 240,000 (+B0) -> 66,455,200
  const size_t O_B0  = 66454400ull;
  const size_t O_STH = 66214400ull;  // aliases W0 (dead after vocab gemm)
  const size_t O_STC = 66316800ull;
  const size_t O_W1  = 66455200ull;  // 160,000 (+B1) -> 66,616,000
  const size_t O_B1  = 66615200ull;
  const size_t TOTAL_FL = 66616000ull;
  const size_t O_H2  = 0;            // 26,214,400 (P0 dead after lstm0)
  const size_t O_XPF = 26214400ull;  // 6,553,600
  const size_t O_XPB = 32768000ull;  // 6,553,600 -> 39,321,600 <= 40M
  const size_t O_EM  = 26214400ull;  // 1,048,576 (after layer1; XP dead)

  if (ws_size < TOTAL_FL * 4ull) {
    report_kernel<<<(out_size + 255) / 256, 256, 0, stream>>>(out, (float)ws_size, out_size);
    return;
  }

  float* P0  = ws + O_P0;
  float* h1  = ws + O_H1;
  float* W0  = ws + O_W0;
  float* B0  = ws + O_B0;
  float* stH = ws + O_STH;
  float* stC = ws + O_STC;
  float* W1  = ws + O_W1;
  float* B1  = ws + O_B1;
  float* h2  = ws + O_H2;
  float* XPF = ws + O_XPF;
  float* XPB = ws + O_XPB;
  float* em  = ws + O_EM;

  pack_kernel<<<256, 256, 0, stream>>>(wih0f, bih0f, bhh0f, wih0b, bih0b, bhh0b,
                                       wih1f, bih1f, bhh1f, wih1b, bih1b, bhh1b,
                                       W0, B0, W1, B1, out);
  // vocab projection: P0[50000][800]
  dim3 g1((50000 + BM - 1) / BM, (800 + BN - 1) / BN);
  gemm_tn<<<g1, 256, 0, stream>>>(emb, W0, B0, P0, 50000, 800, 300);

  // layer 0: one persistent launch, both dirs, gather via sentence
  lstm2<<<B, 256, 0, stream>>>(P0, P0 + 400, 800, sentence, whh0f, whh0b,
                               stH, stC, h1, 0, 0, T, 1, B);

  // layer 1: chunked; both-dir GEMM in one launch; XP/h2 recycle P0 space
  dim3 gc((TCH * B + BM - 1) / BM, (400 + BN - 1) / BN, 2);
  for (int cc = 0; cc < T / TCH; ++cc) {
    int baseF = cc * TCH;
    int baseB = T - TCH - cc * TCH;
    gemm_dual<<<gc, 256, 0, stream>>>(h1, W1, B1, XPF, XPB, baseF, baseB, B);
    lstm2<<<B, 256, 0, stream>>>(XPF, XPB, 400, nullptr, whh1f, whh1b,
                                 stH, stC, h2, baseF, baseB, TCH, cc == 0, B);
  }

  em_kernel<<<(T * B) / 32, 256, 0, stream>>>(h2, wl, bl_, em);
  crf_kernel<<<B / 8, 64, 0, stream>>>(em, tags, start_t, end_t, trans, out, T, B);
  viterbi_kernel<<<B / 8, 64, 0, stream>>>(em, start_t, end_t, trans, out + 1, T, B);
}